// Round 8
// baseline (161.922 us; speedup 1.0000x reference)
//
#include <hip/hip_runtime.h>
#include <math.h>

#define B_ 64
#define S_ 129
#define F_ 768
#define N3 192            // 3*B
#define GSZ 36864         // 192*192

// ws float offsets
#define WS_S1   0
#define WS_S2   49152
#define WS_SQ   98304     // 192 floats (gram diag, fp32)
#define WS_PART 98560     // up to 504 slices x 36864 f32 partial Grams

// out float offsets
#define OUT_LOSS 6340608
#define OUT_NM   6340609
#define OUT_NV   6343681

typedef unsigned int uint;
using short8v = __attribute__((ext_vector_type(8))) short;
using float4v = __attribute__((ext_vector_type(4))) float;

// ---------------- bf16 helpers ----------------
__device__ __forceinline__ uint pack2(float a, float b) {
    uint ua = __float_as_uint(a);
    uint ub = __float_as_uint(b);
    uint ha = (ua + 0x7FFFu + ((ua >> 16) & 1u)) >> 16;
    uint hb = (ub + 0x7FFFu + ((ub >> 16) & 1u)) & 0xFFFF0000u;
    return hb | ha;
}

__device__ __forceinline__ void bf16_store8(char* lds, int row, int g,
                                            float4 v0, float4 v1) {
    uint4 H;
    H.x = pack2(v0.x, v0.y);
    H.y = pack2(v0.z, v0.w);
    H.z = pack2(v1.x, v1.y);
    H.w = pack2(v1.z, v1.w);
    *(uint4*)(lds + row * 128 + ((g ^ (row & 7)) << 4)) = H;
}

__device__ __forceinline__ float4 fma4(float4 a, float4 x, float4 b) {
    float4 r;
    r.x = fmaf(a.x, x.x, b.x); r.y = fmaf(a.y, x.y, b.y);
    r.z = fmaf(a.z, x.z, b.z); r.w = fmaf(a.w, x.w, b.w);
    return r;
}

// ---------------- K1: per-(b,f) sums over S, 8-way S-split + LDS reduce ------------
// Also zeroes sqw (gram diagonal accumulator) and out_loss.
__global__ void k_stats(const float* __restrict__ x,
                        float* __restrict__ s1, float* __restrict__ s2,
                        float* __restrict__ sqw, float* __restrict__ out_loss) {
    __shared__ float4 r1[512], r2[512];
    if (blockIdx.x == 0) {
        if (threadIdx.x == 0) out_loss[0] = 0.0f;
        if (threadIdx.x < N3) sqw[threadIdx.x] = 0.0f;
    }
    int b = blockIdx.x / 3, fg = blockIdx.x % 3;
    int c = threadIdx.x & 63, sp = threadIdx.x >> 6;   // 8-way S split
    int f = fg * 256 + c * 4;
    const float* p = x + (size_t)b * S_ * F_ + f;
    int s0 = sp * 16;
    int se = s0 + 16 + (sp == 7 ? 1 : 0);
    float4 a1 = {0.f,0.f,0.f,0.f}, a2 = {0.f,0.f,0.f,0.f};
#pragma unroll 4
    for (int s = s0; s < se; ++s) {
        float4 v = *(const float4*)(p + s * F_);
        a1.x += v.x; a1.y += v.y; a1.z += v.z; a1.w += v.w;
        a2.x += v.x*v.x; a2.y += v.y*v.y; a2.z += v.z*v.z; a2.w += v.w*v.w;
    }
    r1[threadIdx.x] = a1; r2[threadIdx.x] = a2;
    __syncthreads();
    if (sp == 0) {
        float4 t1 = r1[c], t2 = r2[c];
#pragma unroll
        for (int k = 1; k < 8; ++k) {
            float4 u1 = r1[k * 64 + c], u2 = r2[k * 64 + c];
            t1.x += u1.x; t1.y += u1.y; t1.z += u1.z; t1.w += u1.w;
            t2.x += u2.x; t2.y += u2.y; t2.z += u2.z; t2.w += u2.w;
        }
        *(float4*)(s1 + b * F_ + f) = t1;
        *(float4*)(s2 + b * F_ + f) = t2;
    }
}

// ---------------- K2: fused dom-stats + coef + x_mix/hg gen + MFMA Gram -------------
// 12*sg blocks x 512 threads. sg=42 -> 504 blocks = 2 blocks/CU (VGPR 100 <= 128,
// LDS 2x48K <= 160K): doubles wave-level latency hiding (r6 counters: occupancy 20%,
// everything-low = latency-bound; barriers/prefetch already nulled in r4/r5).
// sg=21 reproduces the r5 champion exactly (ws-size fallback).
// fp32 partials (r7 post-mortem: bf16 partials regressed — stream is L2/L3-resident,
// pack/unpack was pure cost). Epilogue atomicAdds the diagonal into sqw (fp32).
__global__ __launch_bounds__(512, 2)
void k_main(const float* __restrict__ x, const float* __restrict__ hgn,
            const float* __restrict__ s1, const float* __restrict__ s2,
            const float* __restrict__ mean_buf, const float* __restrict__ var_buf,
            const float* __restrict__ lmda, const int* __restrict__ domain,
            const int* __restrict__ d_rand,
            float* __restrict__ xmix, float* __restrict__ out_nm,
            float* __restrict__ out_nv,
            float* __restrict__ part, float* __restrict__ sqw, int sg) {
    __shared__ __align__(16) char LDS[49152];   // 2 planes x 192 rows x 128 B
    __shared__ float NMV[4][64];
    __shared__ float SVV[4][64];

    int tid = threadIdx.x;
    int bid = blockIdx.x;
    int fc = bid % 12, sb = bid / 12;            // sb in [0, sg)
    int f0 = fc * 64;
    int b = tid >> 3, g = tid & 7;
    int w = tid >> 6;
    int wr = (w >> 2) * 96, wc = (w & 3) * 48;
    int lane = tid & 63, m = lane & 15, qd = lane >> 4;

    // depth-2 prefetch: chunks sb (A) and sb+sg (B); sb+sg <= 2*sg-1 <= 83 < S_
    size_t gA = ((size_t)b * S_ + sb) * F_ + f0 + (g << 3);
    float4 XA0 = ((const float4*)(x + gA))[0];
    float4 XA1 = ((const float4*)(x + gA))[1];
    float4 NA0 = ((const float4*)(hgn + gA))[0];
    float4 NA1 = ((const float4*)(hgn + gA))[1];
    size_t gB = ((size_t)b * S_ + sb + sg) * F_ + f0 + (g << 3);
    float4 XB0 = ((const float4*)(x + gB))[0];
    float4 XB1 = ((const float4*)(x + gB))[1];
    float4 NB0 = ((const float4*)(hgn + gB))[0];
    float4 NB1 = ((const float4*)(hgn + gB))[1];

    // ---- folded k_dom: per-(d,f) EMA stats for this block's f-column ----
    if (tid < 256) {
        int d = tid & 3, fl = tid >> 2;
        int f = f0 + fl;
        float a1 = 0.f, a2 = 0.f, cnt = 0.f;
#pragma unroll 8
        for (int bb = 0; bb < B_; ++bb) {
            bool mk = (domain[bb] == d);
            a1  += mk ? s1[bb * F_ + f] : 0.f;
            a2  += mk ? s2[bb * F_ + f] : 0.f;
            cnt += mk ? 1.f : 0.f;
        }
        float nm, nv;
        if (cnt > 0.f) {
            float n = cnt * (float)S_;
            float mu = a1 / n;
            float var = (a2 - n * mu * mu) / fmaxf(n - 1.f, 1.f);
            nm = 0.9f * mean_buf[d * F_ + f] + 0.1f * mu;
            nv = 0.9f * var_buf[d * F_ + f] + 0.1f * var;
        } else {
            nm = mean_buf[d * F_ + f];
            nv = var_buf[d * F_ + f];
        }
        NMV[d][fl] = nm;
        SVV[d][fl] = sqrtf(nv + 1e-6f);
        if (sb == 0) { out_nm[d * F_ + f] = nm; out_nv[d * F_ + f] = nv; }
    }
    __syncthreads();

    // ---- folded k_coef: per-thread mix/hg coefficients, held in regs all kernel ----
    int cb = b * F_ + f0 + (g << 3);
    float4 S1a = ((const float4*)(s1 + cb))[0], S1b = ((const float4*)(s1 + cb))[1];
    float4 S2a = ((const float4*)(s2 + cb))[0], S2b = ((const float4*)(s2 + cb))[1];
    int dm = domain[b];
    int dsd = (dm + d_rand[b]) & 3;              // D == 4
    float lam = lmda[b];
    float4 C1a, C1b, C0a, C0b, HMa, HMb, HSa, HSb;
#define COEF(SC1, SC2, FL, RC1, RC0, RHM, RHS) {            \
        float mu = (SC1) * (1.0f / (float)S_);              \
        float v  = ((SC2) - (float)S_ * mu * mu) * (1.0f / (float)(S_ - 1)); \
        float r  = rsqrtf(v + 1e-6f);                       \
        float sv = SVV[dsd][FL];                            \
        float rs = r * sv;                                  \
        RC1 = lam + (1.0f - lam) * rs;                      \
        RC0 = (1.0f - lam) * (NMV[dsd][FL] - mu * rs);      \
        RHM = NMV[dm][FL];                                  \
        RHS = SVV[dm][FL]; }
    {
        int fb = g << 3;
        COEF(S1a.x, S2a.x, fb + 0, C1a.x, C0a.x, HMa.x, HSa.x);
        COEF(S1a.y, S2a.y, fb + 1, C1a.y, C0a.y, HMa.y, HSa.y);
        COEF(S1a.z, S2a.z, fb + 2, C1a.z, C0a.z, HMa.z, HSa.z);
        COEF(S1a.w, S2a.w, fb + 3, C1a.w, C0a.w, HMa.w, HSa.w);
        COEF(S1b.x, S2b.x, fb + 4, C1b.x, C0b.x, HMb.x, HSb.x);
        COEF(S1b.y, S2b.y, fb + 5, C1b.y, C0b.y, HMb.y, HSb.y);
        COEF(S1b.z, S2b.z, fb + 6, C1b.z, C0b.z, HMb.z, HSb.z);
        COEF(S1b.w, S2b.w, fb + 7, C1b.w, C0b.w, HMb.w, HSb.w);
    }
#undef COEF

    float4v acc[6][3];
#pragma unroll
    for (int i = 0; i < 6; ++i)
#pragma unroll
        for (int j = 0; j < 3; ++j)
            acc[i][j] = (float4v){0.f, 0.f, 0.f, 0.f};

#define STAGE_CHUNK(PL, X0_, X1_, N0_, N1_, GOFF_)                           \
    {                                                                        \
        float4 M0 = fma4(C1a, X0_, C0a);                                     \
        float4 M1 = fma4(C1b, X1_, C0b);                                     \
        ((float4*)(xmix + GOFF_))[0] = M0;                                   \
        ((float4*)(xmix + GOFF_))[1] = M1;                                   \
        float4 H0 = fma4(HSa, N0_, HMa);                                     \
        float4 H1 = fma4(HSb, N1_, HMb);                                     \
        bf16_store8(LDS, (PL) * 192 + b, g, X0_, X1_);                       \
        bf16_store8(LDS, (PL) * 192 + 64 + b, g, M0, M1);                    \
        bf16_store8(LDS, (PL) * 192 + 128 + b, g, H0, H1);                   \
    }

#define MFMA_PLANE(PL)                                                       \
        _Pragma("unroll")                                                    \
        for (int t = 0; t < 2; ++t) {                                        \
            short8v A[6];                                                    \
            _Pragma("unroll")                                                \
            for (int i = 0; i < 6; ++i) {                                    \
                int row = wr + i * 16 + m;                                   \
                int go = (((t << 2) + qd) ^ (row & 7)) << 4;                 \
                A[i] = *(const short8v*)(LDS + ((PL) * 192 + row) * 128 + go); \
            }                                                                \
            _Pragma("unroll")                                                \
            for (int j = 0; j < 3; ++j) {                                    \
                int row = wc + j * 16 + m;                                   \
                int go = (((t << 2) + qd) ^ (row & 7)) << 4;                 \
                short8v Bv = *(const short8v*)(LDS + ((PL) * 192 + row) * 128 + go); \
                _Pragma("unroll")                                            \
                for (int i = 0; i < 6; ++i)                                  \
                    acc[i][j] = __builtin_amdgcn_mfma_f32_16x16x32_bf16(     \
                        A[i], Bv, acc[i][j], 0, 0, 0);                       \
            }                                                                \
        }

    for (int s = sb; s < S_; s += 2 * sg) {
        bool haveB = (s + sg < S_);              // block-uniform
        STAGE_CHUNK(0, XA0, XA1, NA0, NA1, gA);
        if (haveB) STAGE_CHUNK(1, XB0, XB1, NB0, NB1, gB);
        __syncthreads();

        if (s + 2 * sg < S_) {
            gA = ((size_t)b * S_ + s + 2 * sg) * F_ + f0 + (g << 3);
            XA0 = ((const float4*)(x + gA))[0];
            XA1 = ((const float4*)(x + gA))[1];
            NA0 = ((const float4*)(hgn + gA))[0];
            NA1 = ((const float4*)(hgn + gA))[1];
        }
        if (s + 3 * sg < S_) {
            gB = ((size_t)b * S_ + s + 3 * sg) * F_ + f0 + (g << 3);
            XB0 = ((const float4*)(x + gB))[0];
            XB1 = ((const float4*)(x + gB))[1];
            NB0 = ((const float4*)(hgn + gB))[0];
            NB1 = ((const float4*)(hgn + gB))[1];
        }

        MFMA_PLANE(0);
        if (haveB) MFMA_PLANE(1);
        __syncthreads();
    }
#undef STAGE_CHUNK
#undef MFMA_PLANE

    // ---- epilogue: LDS-transpose each 16-row band, coalesced float4 stores,
    //      plus diagonal atomics into sqw ----
    float* T = (float*)LDS;                      // [32][196] f32 (reuses plane 0)
    const int PADW = 196;
    float* dst = part + (size_t)bid * GSZ;       // one exclusive slice per block
    int lrb = (wr ? 16 : 0) + (qd << 2);
    int lr2 = tid >> 4;
#pragma unroll
    for (int i = 0; i < 6; ++i) {
        __syncthreads();
#pragma unroll
        for (int j = 0; j < 3; ++j) {
            int colb = wc + j * 16 + m;
#pragma unroll
            for (int r = 0; r < 4; ++r)
                T[(lrb + r) * PADW + colb] = acc[i][j][r];
        }
        __syncthreads();
        int grow = i * 16 + (lr2 & 15) + (lr2 >> 4) * 96;
#pragma unroll
        for (int k = 0; k < 3; ++k) {
            int c4 = k * 16 + (tid & 15);
            float4 vv = *(const float4*)&T[lr2 * PADW + (c4 << 2)];
            *(float4*)(dst + grow * N3 + (c4 << 2)) = vv;
        }
        if (tid < 32) {
            int dr = i * 16 + (tid & 15) + (tid >> 4) * 96;
            atomicAdd(sqw + dr, T[tid * PADW + dr]);
        }
    }
}

// ---------------- K3: merged row-reduce + triplet loss ----------------
// 192 blocks x 512 threads. Block i reduces Gram row i across npart fp32 slices,
// reads the fp32 diagonal sqw[], computes hard-pos/neg and the loss.
__global__ void k_loss(const float* __restrict__ part, const float* __restrict__ sqw,
                       const int* __restrict__ labels,
                       float* __restrict__ out_loss, int npart) {
    __shared__ float ROW[2][N3];
    __shared__ float SQS[N3];
    __shared__ int   LN[N3];
    __shared__ float APW[3], ANW[3];
    int i = blockIdx.x, tid = threadIdx.x;
    if (tid < 384) {
        int c = tid % N3, h = tid / N3;
        float sacc = 0.f;
#pragma unroll 8
        for (int p = h; p < npart; p += 2)
            sacc += part[(size_t)p * GSZ + i * N3 + c];
        ROW[h][c] = sacc;
    }
    if (tid >= 320) {                            // tid in [320,512): 192 threads
        int c = tid - 320;
        SQS[c] = sqw[c];
        LN[c] = (c < 128) ? labels[c & 63] : -1;
    }
    __syncthreads();
    if (tid < N3) {
        float gij = ROW[0][tid] + ROW[1][tid];
        int li = LN[i];
        float d2 = SQS[i] + SQS[tid] - 2.0f * gij;
        float dist = sqrtf(fmaxf(d2, 1e-12f));
        bool pos = (li == LN[tid]);
        float ap = pos ? dist : -1e30f;
        float an = pos ? 1e30f : dist;
#pragma unroll
        for (int off = 32; off; off >>= 1) {
            ap = fmaxf(ap, __shfl_xor(ap, off));
            an = fminf(an, __shfl_xor(an, off));
        }
        if ((tid & 63) == 0) { APW[tid >> 6] = ap; ANW[tid >> 6] = an; }
    }
    __syncthreads();
    if (tid == 0) {
        float a = fmaxf(fmaxf(APW[0], APW[1]), APW[2]);
        float n = fminf(fminf(ANW[0], ANW[1]), ANW[2]);
        float xv = a - n;
        float sp = fmaxf(xv, 0.0f) + log1pf(expf(-fabsf(xv)));
        atomicAdd(out_loss, sp * (1.0f / (float)N3));
    }
}

extern "C" void kernel_launch(void* const* d_in, const int* in_sizes, int n_in,
                              void* d_out, int out_size, void* d_ws, size_t ws_size,
                              hipStream_t stream) {
    const float* x        = (const float*)d_in[0];
    const float* lmda     = (const float*)d_in[1];
    const float* mean_buf = (const float*)d_in[2];
    const float* var_buf  = (const float*)d_in[3];
    const float* hgn      = (const float*)d_in[4];
    const int*   labels   = (const int*)d_in[5];
    const int*   domain   = (const int*)d_in[6];
    const int*   d_rand   = (const int*)d_in[7];
    float* out = (float*)d_out;
    float* ws  = (float*)d_ws;

    float* sqw  = ws + WS_SQ;
    float* part = ws + WS_PART;

    // sg=42 -> 504 blocks (2/CU). Fallback sg=21 (= r5 champion) if ws too small.
    long wsf = (long)(ws_size / 4);
    int sg = (wsf >= WS_PART + 504L * GSZ) ? 42 : 21;
    int grid = 12 * sg;

    k_stats<<<dim3(192), dim3(512), 0, stream>>>(x, ws + WS_S1, ws + WS_S2,
                                                 sqw, out + OUT_LOSS);
    k_main<<<dim3(grid), dim3(512), 0, stream>>>(
        x, hgn, ws + WS_S1, ws + WS_S2, mean_buf, var_buf,
        lmda, domain, d_rand,
        out, out + OUT_NM, out + OUT_NV, part, sqw, sg);
    k_loss<<<dim3(N3), dim3(512), 0, stream>>>(part, sqw, labels,
                                               out + OUT_LOSS, grid);
}

// Round 9
// 141.543 us; speedup vs baseline: 1.1440x; 1.1440x over previous
//
#include <hip/hip_runtime.h>
#include <math.h>

#define B_ 64
#define S_ 129
#define F_ 768
#define N3 192            // 3*B
#define GSZ 36864         // 192*192
#define GRID_MAIN 252     // 12 f-columns x 21 s-groups

// ws float offsets
#define WS_S1   0
#define WS_S2   49152
#define WS_SQ   98304     // 192 floats (gram diag, fp32)
#define WS_PART 98560     // 252 slices x 36864 f32 partial Grams

// out float offsets
#define OUT_LOSS 6340608
#define OUT_NM   6340609
#define OUT_NV   6343681

typedef unsigned int uint;
using short8v = __attribute__((ext_vector_type(8))) short;
using float4v = __attribute__((ext_vector_type(4))) float;

// ---------------- bf16 helpers ----------------
__device__ __forceinline__ uint pack2(float a, float b) {
    uint ua = __float_as_uint(a);
    uint ub = __float_as_uint(b);
    uint ha = (ua + 0x7FFFu + ((ua >> 16) & 1u)) >> 16;
    uint hb = (ub + 0x7FFFu + ((ub >> 16) & 1u)) & 0xFFFF0000u;
    return hb | ha;
}

__device__ __forceinline__ void bf16_store8(char* lds, int row, int g,
                                            float4 v0, float4 v1) {
    uint4 H;
    H.x = pack2(v0.x, v0.y);
    H.y = pack2(v0.z, v0.w);
    H.z = pack2(v1.x, v1.y);
    H.w = pack2(v1.z, v1.w);
    *(uint4*)(lds + row * 128 + ((g ^ (row & 7)) << 4)) = H;
}

__device__ __forceinline__ float4 fma4(float4 a, float4 x, float4 b) {
    float4 r;
    r.x = fmaf(a.x, x.x, b.x); r.y = fmaf(a.y, x.y, b.y);
    r.z = fmaf(a.z, x.z, b.z); r.w = fmaf(a.w, x.w, b.w);
    return r;
}

// ---------------- K1: per-(b,f) sums over S, 8-way S-split + LDS reduce ------------
// Also zeroes sqw (gram diagonal accumulator) and out_loss.
__global__ void k_stats(const float* __restrict__ x,
                        float* __restrict__ s1, float* __restrict__ s2,
                        float* __restrict__ sqw, float* __restrict__ out_loss) {
    __shared__ float4 r1[512], r2[512];
    if (blockIdx.x == 0) {
        if (threadIdx.x == 0) out_loss[0] = 0.0f;
        if (threadIdx.x < N3) sqw[threadIdx.x] = 0.0f;
    }
    int b = blockIdx.x / 3, fg = blockIdx.x % 3;
    int c = threadIdx.x & 63, sp = threadIdx.x >> 6;   // 8-way S split
    int f = fg * 256 + c * 4;
    const float* p = x + (size_t)b * S_ * F_ + f;
    int s0 = sp * 16;
    int se = s0 + 16 + (sp == 7 ? 1 : 0);
    float4 a1 = {0.f,0.f,0.f,0.f}, a2 = {0.f,0.f,0.f,0.f};
#pragma unroll 4
    for (int s = s0; s < se; ++s) {
        float4 v = *(const float4*)(p + s * F_);
        a1.x += v.x; a1.y += v.y; a1.z += v.z; a1.w += v.w;
        a2.x += v.x*v.x; a2.y += v.y*v.y; a2.z += v.z*v.z; a2.w += v.w*v.w;
    }
    r1[threadIdx.x] = a1; r2[threadIdx.x] = a2;
    __syncthreads();
    if (sp == 0) {
        float4 t1 = r1[c], t2 = r2[c];
#pragma unroll
        for (int k = 1; k < 8; ++k) {
            float4 u1 = r1[k * 64 + c], u2 = r2[k * 64 + c];
            t1.x += u1.x; t1.y += u1.y; t1.z += u1.z; t1.w += u1.w;
            t2.x += u2.x; t2.y += u2.y; t2.z += u2.z; t2.w += u2.w;
        }
        *(float4*)(s1 + b * F_ + f) = t1;
        *(float4*)(s2 + b * F_ + f) = t2;
    }
}

// ---------------- K2: fused dom-stats + coef + x_mix/hg gen + MFMA Gram -------------
// 252 blocks x 512 threads (r5 champion structure — grid 504 regressed in r8:
// partial-slice traffic scales with grid and falls off the L2/L3 knee).
// Two-plane staging, depth-2 prefetch, fp32 partials (bf16 partials regressed, r7).
__global__ __launch_bounds__(512, 2)
void k_main(const float* __restrict__ x, const float* __restrict__ hgn,
            const float* __restrict__ s1, const float* __restrict__ s2,
            const float* __restrict__ mean_buf, const float* __restrict__ var_buf,
            const float* __restrict__ lmda, const int* __restrict__ domain,
            const int* __restrict__ d_rand,
            float* __restrict__ xmix, float* __restrict__ out_nm,
            float* __restrict__ out_nv,
            float* __restrict__ part, float* __restrict__ sqw) {
    __shared__ __align__(16) char LDS[49152];   // 2 planes x 192 rows x 128 B
    __shared__ float NMV[4][64];
    __shared__ float SVV[4][64];

    int tid = threadIdx.x;
    int bid = blockIdx.x;
    int fc = bid % 12, sb = bid / 12;
    int f0 = fc * 64;
    int b = tid >> 3, g = tid & 7;
    int w = tid >> 6;
    int wr = (w >> 2) * 96, wc = (w & 3) * 48;
    int lane = tid & 63, m = lane & 15, qd = lane >> 4;

    // depth-2 prefetch: preload chunks sb (A) and sb+21 (B) before the prologue
    size_t gA = ((size_t)b * S_ + sb) * F_ + f0 + (g << 3);
    float4 XA0 = ((const float4*)(x + gA))[0];
    float4 XA1 = ((const float4*)(x + gA))[1];
    float4 NA0 = ((const float4*)(hgn + gA))[0];
    float4 NA1 = ((const float4*)(hgn + gA))[1];
    size_t gB = ((size_t)b * S_ + sb + 21) * F_ + f0 + (g << 3);  // sb+21 <= 41 < S_
    float4 XB0 = ((const float4*)(x + gB))[0];
    float4 XB1 = ((const float4*)(x + gB))[1];
    float4 NB0 = ((const float4*)(hgn + gB))[0];
    float4 NB1 = ((const float4*)(hgn + gB))[1];

    // ---- folded k_dom: per-(d,f) EMA stats for this block's f-column ----
    if (tid < 256) {
        int d = tid & 3, fl = tid >> 2;
        int f = f0 + fl;
        float a1 = 0.f, a2 = 0.f, cnt = 0.f;
#pragma unroll 8
        for (int bb = 0; bb < B_; ++bb) {
            bool mk = (domain[bb] == d);
            a1  += mk ? s1[bb * F_ + f] : 0.f;
            a2  += mk ? s2[bb * F_ + f] : 0.f;
            cnt += mk ? 1.f : 0.f;
        }
        float nm, nv;
        if (cnt > 0.f) {
            float n = cnt * (float)S_;
            float mu = a1 / n;
            float var = (a2 - n * mu * mu) / fmaxf(n - 1.f, 1.f);
            nm = 0.9f * mean_buf[d * F_ + f] + 0.1f * mu;
            nv = 0.9f * var_buf[d * F_ + f] + 0.1f * var;
        } else {
            nm = mean_buf[d * F_ + f];
            nv = var_buf[d * F_ + f];
        }
        NMV[d][fl] = nm;
        SVV[d][fl] = sqrtf(nv + 1e-6f);
        if (sb == 0) { out_nm[d * F_ + f] = nm; out_nv[d * F_ + f] = nv; }
    }
    __syncthreads();

    // ---- folded k_coef: per-thread mix/hg coefficients, held in regs all kernel ----
    int cb = b * F_ + f0 + (g << 3);
    float4 S1a = ((const float4*)(s1 + cb))[0], S1b = ((const float4*)(s1 + cb))[1];
    float4 S2a = ((const float4*)(s2 + cb))[0], S2b = ((const float4*)(s2 + cb))[1];
    int dm = domain[b];
    int dsd = (dm + d_rand[b]) & 3;              // D == 4
    float lam = lmda[b];
    float4 C1a, C1b, C0a, C0b, HMa, HMb, HSa, HSb;
#define COEF(SC1, SC2, FL, RC1, RC0, RHM, RHS) {            \
        float mu = (SC1) * (1.0f / (float)S_);              \
        float v  = ((SC2) - (float)S_ * mu * mu) * (1.0f / (float)(S_ - 1)); \
        float r  = rsqrtf(v + 1e-6f);                       \
        float sv = SVV[dsd][FL];                            \
        float rs = r * sv;                                  \
        RC1 = lam + (1.0f - lam) * rs;                      \
        RC0 = (1.0f - lam) * (NMV[dsd][FL] - mu * rs);      \
        RHM = NMV[dm][FL];                                  \
        RHS = SVV[dm][FL]; }
    {
        int fb = g << 3;
        COEF(S1a.x, S2a.x, fb + 0, C1a.x, C0a.x, HMa.x, HSa.x);
        COEF(S1a.y, S2a.y, fb + 1, C1a.y, C0a.y, HMa.y, HSa.y);
        COEF(S1a.z, S2a.z, fb + 2, C1a.z, C0a.z, HMa.z, HSa.z);
        COEF(S1a.w, S2a.w, fb + 3, C1a.w, C0a.w, HMa.w, HSa.w);
        COEF(S1b.x, S2b.x, fb + 4, C1b.x, C0b.x, HMb.x, HSb.x);
        COEF(S1b.y, S2b.y, fb + 5, C1b.y, C0b.y, HMb.y, HSb.y);
        COEF(S1b.z, S2b.z, fb + 6, C1b.z, C0b.z, HMb.z, HSb.z);
        COEF(S1b.w, S2b.w, fb + 7, C1b.w, C0b.w, HMb.w, HSb.w);
    }
#undef COEF

    float4v acc[6][3];
#pragma unroll
    for (int i = 0; i < 6; ++i)
#pragma unroll
        for (int j = 0; j < 3; ++j)
            acc[i][j] = (float4v){0.f, 0.f, 0.f, 0.f};

#define STAGE_CHUNK(PL, X0_, X1_, N0_, N1_, GOFF_)                           \
    {                                                                        \
        float4 M0 = fma4(C1a, X0_, C0a);                                     \
        float4 M1 = fma4(C1b, X1_, C0b);                                     \
        ((float4*)(xmix + GOFF_))[0] = M0;                                   \
        ((float4*)(xmix + GOFF_))[1] = M1;                                   \
        float4 H0 = fma4(HSa, N0_, HMa);                                     \
        float4 H1 = fma4(HSb, N1_, HMb);                                     \
        bf16_store8(LDS, (PL) * 192 + b, g, X0_, X1_);                       \
        bf16_store8(LDS, (PL) * 192 + 64 + b, g, M0, M1);                    \
        bf16_store8(LDS, (PL) * 192 + 128 + b, g, H0, H1);                   \
    }

#define MFMA_PLANE(PL)                                                       \
        _Pragma("unroll")                                                    \
        for (int t = 0; t < 2; ++t) {                                        \
            short8v A[6];                                                    \
            _Pragma("unroll")                                                \
            for (int i = 0; i < 6; ++i) {                                    \
                int row = wr + i * 16 + m;                                   \
                int go = (((t << 2) + qd) ^ (row & 7)) << 4;                 \
                A[i] = *(const short8v*)(LDS + ((PL) * 192 + row) * 128 + go); \
            }                                                                \
            _Pragma("unroll")                                                \
            for (int j = 0; j < 3; ++j) {                                    \
                int row = wc + j * 16 + m;                                   \
                int go = (((t << 2) + qd) ^ (row & 7)) << 4;                 \
                short8v Bv = *(const short8v*)(LDS + ((PL) * 192 + row) * 128 + go); \
                _Pragma("unroll")                                            \
                for (int i = 0; i < 6; ++i)                                  \
                    acc[i][j] = __builtin_amdgcn_mfma_f32_16x16x32_bf16(     \
                        A[i], Bv, acc[i][j], 0, 0, 0);                       \
            }                                                                \
        }

    for (int s = sb; s < S_; s += 42) {
        bool haveB = (s + 21 < S_);              // block-uniform
        STAGE_CHUNK(0, XA0, XA1, NA0, NA1, gA);
        if (haveB) STAGE_CHUNK(1, XB0, XB1, NB0, NB1, gB);
        __syncthreads();

        if (s + 42 < S_) {
            gA = ((size_t)b * S_ + s + 42) * F_ + f0 + (g << 3);
            XA0 = ((const float4*)(x + gA))[0];
            XA1 = ((const float4*)(x + gA))[1];
            NA0 = ((const float4*)(hgn + gA))[0];
            NA1 = ((const float4*)(hgn + gA))[1];
        }
        if (s + 63 < S_) {
            gB = ((size_t)b * S_ + s + 63) * F_ + f0 + (g << 3);
            XB0 = ((const float4*)(x + gB))[0];
            XB1 = ((const float4*)(x + gB))[1];
            NB0 = ((const float4*)(hgn + gB))[0];
            NB1 = ((const float4*)(hgn + gB))[1];
        }

        MFMA_PLANE(0);
        if (haveB) MFMA_PLANE(1);
        __syncthreads();
    }
#undef STAGE_CHUNK
#undef MFMA_PLANE

    // ---- epilogue: LDS-transpose each 16-row band, coalesced float4 stores,
    //      plus diagonal atomics into sqw ----
    float* T = (float*)LDS;                      // [32][196] f32 (reuses plane 0)
    const int PADW = 196;
    float* dst = part + (size_t)bid * GSZ;       // one exclusive slice per block
    int lrb = (wr ? 16 : 0) + (qd << 2);
    int lr2 = tid >> 4;
#pragma unroll
    for (int i = 0; i < 6; ++i) {
        __syncthreads();
#pragma unroll
        for (int j = 0; j < 3; ++j) {
            int colb = wc + j * 16 + m;
#pragma unroll
            for (int r = 0; r < 4; ++r)
                T[(lrb + r) * PADW + colb] = acc[i][j][r];
        }
        __syncthreads();
        int grow = i * 16 + (lr2 & 15) + (lr2 >> 4) * 96;
#pragma unroll
        for (int k = 0; k < 3; ++k) {
            int c4 = k * 16 + (tid & 15);
            float4 vv = *(const float4*)&T[lr2 * PADW + (c4 << 2)];
            *(float4*)(dst + grow * N3 + (c4 << 2)) = vv;
        }
        if (tid < 32) {
            int dr = i * 16 + (tid & 15) + (tid >> 4) * 96;
            atomicAdd(sqw + dr, T[tid * PADW + dr]);
        }
    }
}

// ---------------- K3: merged row-reduce + triplet loss (float4 reduction) ----------
// 192 blocks x 512 threads. r9: the slice reduction is float4-vectorized —
// 384 threads = 48 column-quads x 8 slice-ways (~32 vec iters each, was 126
// scalar latency-bound iters), then an 8-way LDS combine whose read address is
// h*768 + tid*4 (consecutive per lane -> bank-conflict-free).
__global__ void k_loss(const float* __restrict__ part, const float* __restrict__ sqw,
                       const int* __restrict__ labels,
                       float* __restrict__ out_loss, int npart) {
    __shared__ float4 ROW4[8][48];
    __shared__ float SQS[N3];
    __shared__ int   LN[N3];
    __shared__ float APW[3], ANW[3];
    int i = blockIdx.x, tid = threadIdx.x;
    if (tid < 384) {
        int c4 = tid % 48, h = tid / 48;         // 48 quads x 8 ways
        const float* prow = part + (size_t)i * N3 + (c4 << 2);
        float4 sacc = {0.f, 0.f, 0.f, 0.f};
#pragma unroll 4
        for (int p = h; p < npart; p += 8) {
            float4 v = *(const float4*)(prow + (size_t)p * GSZ);
            sacc.x += v.x; sacc.y += v.y; sacc.z += v.z; sacc.w += v.w;
        }
        ROW4[h][c4] = sacc;
    }
    if (tid >= 320) {                            // tid in [320,512): 192 threads
        int c = tid - 320;
        SQS[c] = sqw[c];
        LN[c] = (c < 128) ? labels[c & 63] : -1;
    }
    __syncthreads();
    if (tid < N3) {
        const float* R = (const float*)ROW4;     // [8][192], addr = h*768 + tid*4
        float gij = 0.f;
#pragma unroll
        for (int h = 0; h < 8; ++h) gij += R[h * N3 + tid];
        int li = LN[i];
        float d2 = SQS[i] + SQS[tid] - 2.0f * gij;
        float dist = sqrtf(fmaxf(d2, 1e-12f));
        bool pos = (li == LN[tid]);
        float ap = pos ? dist : -1e30f;
        float an = pos ? 1e30f : dist;
#pragma unroll
        for (int off = 32; off; off >>= 1) {
            ap = fmaxf(ap, __shfl_xor(ap, off));
            an = fminf(an, __shfl_xor(an, off));
        }
        if ((tid & 63) == 0) { APW[tid >> 6] = ap; ANW[tid >> 6] = an; }
    }
    __syncthreads();
    if (tid == 0) {
        float a = fmaxf(fmaxf(APW[0], APW[1]), APW[2]);
        float n = fminf(fminf(ANW[0], ANW[1]), ANW[2]);
        float xv = a - n;
        float sp = fmaxf(xv, 0.0f) + log1pf(expf(-fabsf(xv)));
        atomicAdd(out_loss, sp * (1.0f / (float)N3));
    }
}

extern "C" void kernel_launch(void* const* d_in, const int* in_sizes, int n_in,
                              void* d_out, int out_size, void* d_ws, size_t ws_size,
                              hipStream_t stream) {
    const float* x        = (const float*)d_in[0];
    const float* lmda     = (const float*)d_in[1];
    const float* mean_buf = (const float*)d_in[2];
    const float* var_buf  = (const float*)d_in[3];
    const float* hgn      = (const float*)d_in[4];
    const int*   labels   = (const int*)d_in[5];
    const int*   domain   = (const int*)d_in[6];
    const int*   d_rand   = (const int*)d_in[7];
    float* out = (float*)d_out;
    float* ws  = (float*)d_ws;

    float* sqw  = ws + WS_SQ;
    float* part = ws + WS_PART;

    k_stats<<<dim3(192), dim3(512), 0, stream>>>(x, ws + WS_S1, ws + WS_S2,
                                                 sqw, out + OUT_LOSS);
    k_main<<<dim3(GRID_MAIN), dim3(512), 0, stream>>>(
        x, hgn, ws + WS_S1, ws + WS_S2, mean_buf, var_buf,
        lmda, domain, d_rand,
        out, out + OUT_NM, out + OUT_NV, part, sqw);
    k_loss<<<dim3(N3), dim3(512), 0, stream>>>(part, sqw, labels,
                                               out + OUT_LOSS, GRID_MAIN);
}